// Round 4
// baseline (173.844 us; speedup 1.0000x reference)
//
#include <hip/hip_runtime.h>
#include <math.h>

// Problem constants
#define BATCH 16
#define CIN 32
#define COUT 96
#define WH 64
#define IMG (WH*WH)              // 4096
#define NPIX (BATCH*IMG)         // 65536 per channel
#define YELEMS (BATCH*COUT*IMG)  // 6291456
#define NPART 128                // partials per channel: 16 b * 8 rowg
#define PWELEMS (6*CIN*144)      // 27648 packed weights (6 groups x 32 c x 16 oc x 9)

// ---------------------------------------------------------------------------
// weight pack: gather the 9 live taps per (oc, c) into a dense buffer
// pw[g][c][o*9+tap], g = cfg*2+chg (6 groups of 16 out-channels).
// Written into d_out (fully overwritten by bn_tanh afterwards).
// ---------------------------------------------------------------------------
__global__ __launch_bounds__(256) void pack_w_kernel(
    const float* __restrict__ w, float* __restrict__ pw)
{
    int e = blockIdx.x * 256 + threadIdx.x;
    if (e >= PWELEMS) return;
    int g   = e / (CIN * 144);
    int rem = e % (CIN * 144);
    int c   = rem / 144;
    int kk  = rem % 144;
    int o   = kk / 9;
    int tap = kk % 9;
    int cfg = g >> 1, chg = g & 1;
    int d   = cfg + 1;
    int oc  = cfg * 32 + chg * 16 + o;
    int du  = tap / 3, dv = tap % 3;
    pw[e] = w[(((size_t)oc * CIN + c) * 65 + (32 + (du - 1) * d)) * 65
              + (32 + (dv - 1) * d)];
}

#define GLDS(src, dst) __builtin_amdgcn_global_load_lds( \
    (const __attribute__((address_space(1))) void*)(src), \
    (__attribute__((address_space(3))) void*)(dst), 16, 0, 0)

// ---------------------------------------------------------------------------
// conv + per-block stats
// grid = 16 b * 3 cfg * 2 chgroup * 8 rowgroup = 768 blocks ; block 256 ; 3 blk/CU
// Per block: 16 out-channels x 8 rows x 64 cols. Per thread: 2 rows x 1 col x 16 oc.
// 18 LDS values per thread per channel feed 288 FMAs (LDS pipe no longer the bound).
// 2 channels staged per barrier round (double-buffered global_load_lds).
// ---------------------------------------------------------------------------
__global__ __launch_bounds__(256, 3) void conv_stats_kernel(
    const float* __restrict__ x, const float* __restrict__ pw,
    float* __restrict__ y, float* __restrict__ psum, float* __restrict__ psq)
{
    int bid  = blockIdx.x;
    int rowg = bid & 7;            // 8 row groups of 8 rows
    int chg  = (bid >> 3) & 1;     // 2 out-channel groups of 16
    int rest = bid >> 4;           // 0..47
    int cfg  = rest % 3;
    int b    = rest / 3;
    int d    = cfg + 1;            // dilation 1,2,3 (block-uniform)
    int ocb  = cfg * 32 + chg * 16;
    int i0   = rowg * 8;

    int t  = threadIdx.x;
    int j  = t & 63;               // column
    int wv = t >> 6;               // wave 0..3
    int li = wv * 2;               // local output row base (0,2,4,6)

    // 4 staging buffers: [round parity][channel-in-round][16 rows x 64 cols]
    __shared__ float xs[2][2][16 * 64];
    __shared__ float red[4][32];

    // staging addresses (constant over channel loop)
    int rr = t >> 4;               // 0..15 (row in tile)
    int cc4 = (t & 15) * 4;        // col (float4)
    int gi = (i0 - 3 + rr) & 63;   // circular source row
    const float* xsrc = x + (size_t)b * CIN * IMG + gi * 64 + cc4;

    int jm = (j - d) & 63, jp = (j + d) & 63;

    float accx[16], accy[16];
#pragma unroll
    for (int o = 0; o < 16; o++) { accx[o] = 0.f; accy[o] = 0.f; }

    // dense packed weight slab for this block: 32 channels x 144 floats, L2-hot
    const float* wslab = pw + (size_t)(cfg * 2 + chg) * CIN * 144;

    // prefetch round 0 (channels 0,1)
    GLDS(xsrc,       &xs[0][0][t * 4]);
    GLDS(xsrc + IMG, &xs[0][1][t * 4]);

#pragma unroll 1
    for (int k = 0; k < 16; k++) {
        __syncthreads();  // xs[k&1] ready; readers of xs[(k+1)&1] done
        if (k < 15) {
            const float* nsrc = xsrc + (size_t)(2 * k + 2) * IMG;
            GLDS(nsrc,       &xs[(k + 1) & 1][0][t * 4]);
            GLDS(nsrc + IMG, &xs[(k + 1) & 1][1][t * 4]);
        }

        // gather the 18 x-values per channel (rows li..li+1, cols jm/j/jp, 3 du)
        float xrx[2][3][3], xry[2][3][3];
#pragma unroll
        for (int ch = 0; ch < 2; ch++) {
            const float* xb = &xs[k & 1][ch][0];
#pragma unroll
            for (int du = 0; du < 3; du++) {
                const float* r0 = xb + (li + 3 + (du - 1) * d) * 64;
                xrx[ch][du][0] = r0[jm];      xry[ch][du][0] = r0[64 + jm];
                xrx[ch][du][1] = r0[j];       xry[ch][du][1] = r0[64 + j];
                xrx[ch][du][2] = r0[jp];      xry[ch][du][2] = r0[64 + jp];
            }
        }

        // 2 channels x 16 oc x 9 taps x 2 rows = 576 FMAs per thread per round
#pragma unroll
        for (int ch = 0; ch < 2; ch++) {
            const float* wc = wslab + (2 * k + ch) * 144;  // uniform -> s_load
#pragma unroll
            for (int o = 0; o < 16; o++) {
#pragma unroll
                for (int du = 0; du < 3; du++) {
#pragma unroll
                    for (int dv = 0; dv < 3; dv++) {
                        float wvv = wc[o * 9 + du * 3 + dv];
                        accx[o] = fmaf(xrx[ch][du][dv], wvv, accx[o]);
                        accy[o] = fmaf(xry[ch][du][dv], wvv, accy[o]);
                    }
                }
            }
        }
    }

    // write y (coalesced over j) + per-thread sum/sumsq per channel
    float s[16], q[16];
#pragma unroll
    for (int o = 0; o < 16; o++) {
        size_t base = ((size_t)b * COUT + (ocb + o)) * IMG;
        float v0 = accx[o], v1 = accy[o];
        y[base + (size_t)(i0 + li) * WH + j]     = v0;
        y[base + (size_t)(i0 + li + 1) * WH + j] = v1;
        s[o] = v0 + v1;
        q[o] = fmaf(v0, v0, v1 * v1);
    }

    // wave butterfly reduce (64 lanes)
#pragma unroll
    for (int o = 0; o < 16; o++) {
        for (int m = 1; m < 64; m <<= 1) {
            s[o] += __shfl_xor(s[o], m, 64);
            q[o] += __shfl_xor(q[o], m, 64);
        }
    }
    if ((t & 63) == 0) {
#pragma unroll
        for (int o = 0; o < 16; o++) { red[wv][o] = s[o]; red[wv][16 + o] = q[o]; }
    }
    __syncthreads();
    if (t < 32) {
        float v = red[0][t] + red[1][t] + red[2][t] + red[3][t];
        int o = t & 15;
        int slot = (ocb + o) * NPART + b * 8 + rowg;
        if (t < 16) psum[slot] = v; else psq[slot] = v;
    }
}

// ---------------------------------------------------------------------------
// fused finalize + BN + tanh
// grid = 16*96 = 1536 blocks, block 256; each block owns one (b,ch) 64x64 image.
// ---------------------------------------------------------------------------
__device__ __forceinline__ float fast_tanh(float xv) {
    float e = __expf(2.0f * xv);
    return fmaf(-2.0f, __builtin_amdgcn_rcpf(e + 1.0f), 1.0f);
}

__global__ __launch_bounds__(256) void bn_tanh_kernel(
    const float* __restrict__ ybuf, const float* __restrict__ psum,
    const float* __restrict__ psq, const float* __restrict__ gamma,
    const float* __restrict__ beta, float* __restrict__ out)
{
    __shared__ float part[4];
    __shared__ float sc[2];
    int t  = threadIdx.x;
    int ch = blockIdx.x % COUT;

    float s = 0.f, q = 0.f;
    if (t < NPART) { s = psum[ch * NPART + t]; q = psq[ch * NPART + t]; }
    for (int m = 1; m < 64; m <<= 1) {
        s += __shfl_xor(s, m, 64);
        q += __shfl_xor(q, m, 64);
    }
    if (t < NPART && (t & 63) == 0) { part[t >> 6] = s; part[2 + (t >> 6)] = q; }
    __syncthreads();
    if (t == 0) {
        const float inv_n = 1.0f / (float)NPIX;
        float S = part[0] + part[1], Q = part[2] + part[3];
        float mean = S * inv_n;
        float var  = Q * inv_n - mean * mean;
        float a    = gamma[ch] * rsqrtf(var + 1e-5f);
        sc[0] = a;
        sc[1] = beta[ch] - mean * a;
    }
    __syncthreads();

    float a = sc[0], bsh = sc[1];
    size_t base4 = (size_t)blockIdx.x * 1024;  // float4 units
#pragma unroll
    for (int k = 0; k < 4; k++) {
        size_t e4 = base4 + k * 256 + t;
        float4 v = ((const float4*)ybuf)[e4];
        float4 r;
        r.x = fast_tanh(fmaf(v.x, a, bsh));
        r.y = fast_tanh(fmaf(v.y, a, bsh));
        r.z = fast_tanh(fmaf(v.z, a, bsh));
        r.w = fast_tanh(fmaf(v.w, a, bsh));
        ((float4*)out)[e4] = r;
    }
}

extern "C" void kernel_launch(void* const* d_in, const int* in_sizes, int n_in,
                              void* d_out, int out_size, void* d_ws, size_t ws_size,
                              hipStream_t stream) {
    const float* x     = (const float*)d_in[0];
    const float* w     = (const float*)d_in[1];
    // d_in[2] = mask: tap positions known analytically (3x3 dilated, centered at 32)
    const float* gamma = (const float*)d_in[3];
    const float* beta  = (const float*)d_in[4];
    float* out = (float*)d_out;

    float* ws    = (float*)d_ws;
    float* ybuf  = ws;                       // 6291456 floats
    float* psum  = ybuf + YELEMS;            // 96*128
    float* psq   = psum + COUT * NPART;      // 96*128

    // packed weights live in d_out's front 110 KB; conv reads them while
    // writing only ybuf (d_ws); bn_tanh later overwrites all of d_out.
    float* pwbuf = out;

    pack_w_kernel<<<(PWELEMS + 255) / 256, 256, 0, stream>>>(w, pwbuf);
    conv_stats_kernel<<<768, 256, 0, stream>>>(x, pwbuf, ybuf, psum, psq);
    bn_tanh_kernel<<<BATCH * COUT, 256, 0, stream>>>(ybuf, psum, psq, gamma, beta, out);
}

// Round 5
// 120.813 us; speedup vs baseline: 1.4389x; 1.4389x over previous
//
#include <hip/hip_runtime.h>
#include <math.h>

// Problem constants
#define BATCH 16
#define CIN 32
#define COUT 96
#define WH 64
#define IMG (WH*WH)              // 4096
#define NPIX (BATCH*IMG)         // 65536 per channel
#define YELEMS (BATCH*COUT*IMG)  // 6291456
#define NPART 256                // partials per channel: 16 b * 16 rowg
#define PWELEMS (3*9*32*32)      // 27648 packed bf16 weights
#define XTELEMS (BATCH*IMG*CIN)  // 2097152 bf16 transposed x

typedef __attribute__((ext_vector_type(8))) short short8;
typedef __attribute__((ext_vector_type(4))) float floatx4;

__device__ __forceinline__ unsigned short f2bf(float f) {
    union { float f; unsigned u; } v; v.f = f;
    unsigned r = v.u + 0x7FFFu + ((v.u >> 16) & 1u);  // RNE
    return (unsigned short)(r >> 16);
}

#define GLDS(src, dst) __builtin_amdgcn_global_load_lds( \
    (const __attribute__((address_space(1))) void*)(src), \
    (__attribute__((address_space(3))) void*)(dst), 16, 0, 0)

// ---------------------------------------------------------------------------
// pack weights: pw[cfg][tap][oc32][c32] bf16 (only the 9 live taps per cfg)
// ---------------------------------------------------------------------------
__global__ __launch_bounds__(256) void packw_kernel(
    const float* __restrict__ w, unsigned short* __restrict__ pw)
{
    int e = blockIdx.x * 256 + threadIdx.x;
    if (e >= PWELEMS) return;
    int cfg = e / (9 * 1024);
    int rem = e % (9 * 1024);
    int tap = rem >> 10;
    int oc  = (rem >> 5) & 31;
    int c   = rem & 31;
    int d   = cfg + 1;
    int du  = tap / 3, dv = tap % 3;
    size_t idx = (((size_t)(cfg * 32 + oc) * CIN + c) * 65 + (32 + (du - 1) * d)) * 65
                 + (32 + (dv - 1) * d);
    pw[e] = f2bf(w[idx]);
}

// ---------------------------------------------------------------------------
// transpose x: [b][c][pix] fp32 -> xT [b][pix][c] bf16 (channel-minor).
// Reads coalesced over pix per c; writes 64B contiguous per thread.
// ---------------------------------------------------------------------------
__global__ __launch_bounds__(256) void xt_kernel(
    const float* __restrict__ x, unsigned short* __restrict__ xT)
{
    int t   = blockIdx.x * 256 + threadIdx.x;  // 65536 = 16 b * 4096 pix
    int b   = t >> 12;
    int pix = t & 4095;
    const float* xb = x + (size_t)b * CIN * IMG + pix;
    unsigned packed[16];
#pragma unroll
    for (int c2 = 0; c2 < 16; c2++) {
        unsigned short lo = f2bf(xb[(size_t)(2 * c2) * IMG]);
        unsigned short hi = f2bf(xb[(size_t)(2 * c2 + 1) * IMG]);
        packed[c2] = (unsigned)lo | ((unsigned)hi << 16);
    }
    uint4* dst = (uint4*)(xT + (size_t)t * 32);
#pragma unroll
    for (int k = 0; k < 4; k++)
        dst[k] = make_uint4(packed[4 * k], packed[4 * k + 1],
                            packed[4 * k + 2], packed[4 * k + 3]);
}

// ---------------------------------------------------------------------------
// implicit-GEMM conv via MFMA 16x16x32 bf16 + per-block stats.
// grid = 16 b * 3 cfg * 16 rowg = 768 blocks ; block 256 (4 waves) ; 3 blk/CU.
// Block: 32 oc (one cfg) x 4 rows x 64 cols. Wave: 1 row; 4 col-groups of 16.
// Per col-group: 9 taps, each = 1 ds_read_b128 B-frag (x[c0..7] contiguous) and
// 2 MFMAs (oc halves), K=32 channels per MFMA. Weights preloaded as 18 A-frags.
// ---------------------------------------------------------------------------
__global__ __launch_bounds__(256, 3) void conv_mfma_kernel(
    const unsigned short* __restrict__ xT, const unsigned short* __restrict__ pw,
    float* __restrict__ y, float* __restrict__ psum, float* __restrict__ psq)
{
    int bid  = blockIdx.x;
    int rowg = bid & 15;
    int rest = bid >> 4;         // 0..47
    int cfg  = rest % 3;
    int b    = rest / 3;
    int d    = cfg + 1;
    int i0   = rowg * 4;

    int t    = threadIdx.x;
    int wv   = t >> 6;
    int lane = t & 63;
    int l15  = lane & 15;
    int quad = lane >> 4;

    // 10 rows (i0-3 .. i0+6, circular) x 64 cols x 32 ch bf16 = 40 KB
    __shared__ __align__(16) unsigned short tile[10 * 64 * 32];
    __shared__ float red_s[4][32];
    __shared__ float red_q[4][32];

    // stage tile: one 4 KB row slab per GLDS round (256 thr x 16 B)
    const unsigned short* xTb = xT + (size_t)b * IMG * 32;
#pragma unroll
    for (int rr = 0; rr < 10; rr++) {
        int gi = (i0 - 3 + rr) & 63;
        GLDS(xTb + (size_t)gi * 64 * 32 + t * 8, &tile[rr * 2048 + t * 8]);
    }

    // A-frags: lane l holds w[oc = h*16 + l15][c = quad*8 .. +8] for each tap
    const unsigned short* pwc = pw + (size_t)cfg * 9 * 32 * 32;
    short8 af[2][9];
#pragma unroll
    for (int h = 0; h < 2; h++)
#pragma unroll
        for (int tap = 0; tap < 9; tap++)
            af[h][tap] = *(const short8*)(pwc + ((tap * 32 + h * 16 + l15) * 32 + quad * 8));

    __syncthreads();  // drains GLDS (vmcnt) for all waves

    float ss[2][4], qq[2][4];
#pragma unroll
    for (int h = 0; h < 2; h++)
#pragma unroll
        for (int r = 0; r < 4; r++) { ss[h][r] = 0.f; qq[h][r] = 0.f; }

    int row = i0 + wv;
    size_t ybase = ((size_t)b * COUT + cfg * 32) * IMG + (size_t)row * WH;

#pragma unroll 1
    for (int cg = 0; cg < 4; cg++) {
        floatx4 acc0 = {0.f, 0.f, 0.f, 0.f};
        floatx4 acc1 = {0.f, 0.f, 0.f, 0.f};
#pragma unroll
        for (int du = 0; du < 3; du++) {
            int rowloc = wv + 3 + (du - 1) * d;        // 0..9
            const unsigned short* rbase = &tile[rowloc * 2048 + quad * 8];
#pragma unroll
            for (int dv = 0; dv < 3; dv++) {
                int col = (cg * 16 + l15 + (dv - 1) * d) & 63;
                short8 bf = *(const short8*)(rbase + col * 32);
                acc0 = __builtin_amdgcn_mfma_f32_16x16x32_bf16(af[0][du * 3 + dv], bf, acc0, 0, 0, 0);
                acc1 = __builtin_amdgcn_mfma_f32_16x16x32_bf16(af[1][du * 3 + dv], bf, acc1, 0, 0, 0);
            }
        }
        // D layout: oc_local(m) = quad*4 + r (+16 for half 1), col = cg*16 + l15
        int colg = cg * 16 + l15;
#pragma unroll
        for (int r = 0; r < 4; r++) {
            float v0 = acc0[r], v1 = acc1[r];
            int m0 = quad * 4 + r;
            y[ybase + (size_t)m0 * IMG + colg]        = v0;
            y[ybase + (size_t)(16 + m0) * IMG + colg] = v1;
            ss[0][r] += v0; qq[0][r] = fmaf(v0, v0, qq[0][r]);
            ss[1][r] += v1; qq[1][r] = fmaf(v1, v1, qq[1][r]);
        }
    }

    // stats: reduce over the 16 column-lanes (same quad) -> per-oc row sums
#pragma unroll
    for (int h = 0; h < 2; h++)
#pragma unroll
        for (int r = 0; r < 4; r++) {
            float s = ss[h][r], q = qq[h][r];
            for (int m = 1; m < 16; m <<= 1) {
                s += __shfl_xor(s, m, 64);
                q += __shfl_xor(q, m, 64);
            }
            if (l15 == 0) {
                red_s[wv][h * 16 + quad * 4 + r] = s;
                red_q[wv][h * 16 + quad * 4 + r] = q;
            }
        }
    __syncthreads();
    if (t < 32) {
        float S = red_s[0][t] + red_s[1][t] + red_s[2][t] + red_s[3][t];
        psum[(size_t)(cfg * 32 + t) * NPART + b * 16 + rowg] = S;
    } else if (t < 64) {
        int o = t - 32;
        float Q = red_q[0][o] + red_q[1][o] + red_q[2][o] + red_q[3][o];
        psq[(size_t)(cfg * 32 + o) * NPART + b * 16 + rowg] = Q;
    }
}

// ---------------------------------------------------------------------------
// fused finalize + BN + tanh
// grid = 16*96 = 1536 blocks, block 256; each block owns one (b,ch) 64x64 image.
// ---------------------------------------------------------------------------
__device__ __forceinline__ float fast_tanh(float xv) {
    float e = __expf(2.0f * xv);
    return fmaf(-2.0f, __builtin_amdgcn_rcpf(e + 1.0f), 1.0f);
}

__global__ __launch_bounds__(256) void bn_tanh_kernel(
    const float* __restrict__ ybuf, const float* __restrict__ psum,
    const float* __restrict__ psq, const float* __restrict__ gamma,
    const float* __restrict__ beta, float* __restrict__ out)
{
    __shared__ float part[8];
    __shared__ float sc[2];
    int t  = threadIdx.x;
    int ch = blockIdx.x % COUT;

    float s = psum[(size_t)ch * NPART + t];
    float q = psq[(size_t)ch * NPART + t];
    for (int m = 1; m < 64; m <<= 1) {
        s += __shfl_xor(s, m, 64);
        q += __shfl_xor(q, m, 64);
    }
    if ((t & 63) == 0) { part[t >> 6] = s; part[4 + (t >> 6)] = q; }
    __syncthreads();
    if (t == 0) {
        const float inv_n = 1.0f / (float)NPIX;
        float S = part[0] + part[1] + part[2] + part[3];
        float Q = part[4] + part[5] + part[6] + part[7];
        float mean = S * inv_n;
        float var  = Q * inv_n - mean * mean;
        float a    = gamma[ch] * rsqrtf(var + 1e-5f);
        sc[0] = a;
        sc[1] = beta[ch] - mean * a;
    }
    __syncthreads();

    float a = sc[0], bsh = sc[1];
    size_t base4 = (size_t)blockIdx.x * 1024;  // float4 units
#pragma unroll
    for (int k = 0; k < 4; k++) {
        size_t e4 = base4 + k * 256 + t;
        float4 v = ((const float4*)ybuf)[e4];
        float4 r;
        r.x = fast_tanh(fmaf(v.x, a, bsh));
        r.y = fast_tanh(fmaf(v.y, a, bsh));
        r.z = fast_tanh(fmaf(v.z, a, bsh));
        r.w = fast_tanh(fmaf(v.w, a, bsh));
        ((float4*)out)[e4] = r;
    }
}

extern "C" void kernel_launch(void* const* d_in, const int* in_sizes, int n_in,
                              void* d_out, int out_size, void* d_ws, size_t ws_size,
                              hipStream_t stream) {
    const float* x     = (const float*)d_in[0];
    const float* w     = (const float*)d_in[1];
    // d_in[2] = mask: tap positions known analytically (3x3 dilated, centered at 32)
    const float* gamma = (const float*)d_in[3];
    const float* beta  = (const float*)d_in[4];
    float* out = (float*)d_out;

    float* ws   = (float*)d_ws;
    float* ybuf = ws;                        // 6291456 floats (25 MB)
    float* psum = ybuf + YELEMS;             // 96*256
    float* psq  = psum + COUT * NPART;       // 96*256

    // xT (4 MB) + pw (54 KB) live in d_out's front; conv reads them while
    // writing only ybuf (d_ws); bn_tanh later overwrites all of d_out.
    unsigned short* xT = (unsigned short*)d_out;            // 2097152 bf16
    unsigned short* pw = xT + XTELEMS;                      // 27648 bf16

    packw_kernel<<<(PWELEMS + 255) / 256, 256, 0, stream>>>(w, pw);
    xt_kernel<<<NPIX / 256, 256, 0, stream>>>(x, xT);
    conv_mfma_kernel<<<768, 256, 0, stream>>>(xT, pw, ybuf, psum, psq);
    bn_tanh_kernel<<<BATCH * COUT, 256, 0, stream>>>(ybuf, psum, psq, gamma, beta, out);
}